// Round 3
// baseline (88.826 us; speedup 1.0000x reference)
//
#include <hip/hip_runtime.h>
#include <hip/hip_bf16.h>
#include <stdint.h>

// CatLayer: out[i,j,b,c] = sum_k W[c,k] * leaky(concat(x_i, x_j))[k] + bias[c]
// Factorization: leaky commutes with concat =>
//   out[i,j,b,c] = P[i*16+b, c] + Q[j*16+b, c]   (bias folded into P)
//   [P|Q] = leaky(x).reshape(1536,512) @ [W[:, :512]^T | W[:, 512:]^T]
// Kernel 1: fused convert+GEMM (M=1536,K=512,N=1024) -> PQ f32 in ws.
// Kernel 2: combine, write-bound (302 MB f32). Each block writes a 384 KB
//           CONTIGUOUS run (block = (i, jh); j-range x all b,c) for DRAM
//           page locality; p held in regs; q from L2; nt stores.

typedef __attribute__((ext_vector_type(8))) short short8;
typedef __attribute__((ext_vector_type(4))) short short4v;
typedef __attribute__((ext_vector_type(4))) float f32x4;

#define L_DIM 96
#define B_DIM 16
#define C_DIM 512
#define M_DIM 1536   // L*B
#define K_DIM 512
#define N_DIM 1024   // 2*C

__device__ inline unsigned short f32_to_bf16(float f) {
    union { float f; uint32_t u; } c; c.f = f;
    uint32_t u = c.u;
    uint32_t r = (u + 0x7FFFu + ((u >> 16) & 1u)) >> 16;  // RNE
    return (unsigned short)r;
}

// ---- fused GEMM: stage f32 x/W -> leaky+bf16 -> LDS -> MFMA ----
#define LDS_STRIDE 40   // 32 + 8 pad
__global__ __launch_bounds__(256) void gemm_pq(const float* __restrict__ x,
                                               const float* __restrict__ W,
                                               const float* __restrict__ bias,
                                               float* __restrict__ C) {
    __shared__ unsigned short As[128 * LDS_STRIDE];
    __shared__ unsigned short Bs[128 * LDS_STRIDE];
    const int bm = blockIdx.x;            // 0..11
    const int bn = blockIdx.y;            // 0..7
    const int tid = threadIdx.x;
    const int lane = tid & 63;
    const int w  = tid >> 6;
    const int wr = w >> 1, wc = w & 1;    // wave -> 64x64 quadrant
    const int l15 = lane & 15, l4 = lane >> 4;

    const float* wbase = (bn < 4) ? (W + (size_t)(bn * 128) * N_DIM)
                                  : (W + (size_t)(bn * 128 - C_DIM) * N_DIM + C_DIM);
    const float* xbase = x + (size_t)(bm * 128) * K_DIM;

    f32x4 acc[4][4] = {};

    for (int kt = 0; kt < K_DIM / 32; ++kt) {
        __syncthreads();
#pragma unroll
        for (int r = 0; r < 4; ++r) {
            int chunk = tid + 256 * r;
            int row = chunk >> 3;
            int kc  = (chunk & 7) << 2;
            f32x4 va = *(const f32x4*)(xbase + (size_t)row * K_DIM + kt * 32 + kc);
            short4v sa;
#pragma unroll
            for (int e = 0; e < 4; ++e) {
                float f = va[e];
                f = f > 0.f ? f : 0.1f * f;
                sa[e] = (short)f32_to_bf16(f);
            }
            *(short4v*)(&As[row * LDS_STRIDE + kc]) = sa;
            f32x4 vb = *(const f32x4*)(wbase + (size_t)row * N_DIM + kt * 32 + kc);
            short4v sb;
#pragma unroll
            for (int e = 0; e < 4; ++e) sb[e] = (short)f32_to_bf16(vb[e]);
            *(short4v*)(&Bs[row * LDS_STRIDE + kc]) = sb;
        }
        __syncthreads();
        short8 a[4], b[4];
#pragma unroll
        for (int m = 0; m < 4; ++m)
            a[m] = *(const short8*)(&As[(wr * 64 + m * 16 + l15) * LDS_STRIDE + l4 * 8]);
#pragma unroll
        for (int n = 0; n < 4; ++n)
            b[n] = *(const short8*)(&Bs[(wc * 64 + n * 16 + l15) * LDS_STRIDE + l4 * 8]);
#pragma unroll
        for (int m = 0; m < 4; ++m)
#pragma unroll
            for (int n = 0; n < 4; ++n)
                acc[m][n] = __builtin_amdgcn_mfma_f32_16x16x32_bf16(a[m], b[n], acc[m][n], 0, 0, 0);
    }

#pragma unroll
    for (int m = 0; m < 4; ++m) {
#pragma unroll
        for (int n = 0; n < 4; ++n) {
            int col = bn * 128 + wc * 64 + n * 16 + l15;
            float bv = (col < C_DIM) ? bias[col] : 0.f;
#pragma unroll
            for (int i = 0; i < 4; ++i) {
                int row = bm * 128 + wr * 64 + m * 16 + l4 * 4 + i;
                C[(size_t)row * N_DIM + col] = acc[m][n][i] + bv;
            }
        }
    }
}

// ---- combine v3: block = (i, jh); writes j in [jh*12, jh*12+12) x all (b,c)
//      = 12 x 32 KB contiguous. Thread owns 4 (b,c4) slots; p in regs. ----
__global__ __launch_bounds__(512) void combine_k(const f32x4* __restrict__ PQ4,
                                                 f32x4* __restrict__ out4) {
    const int i  = blockIdx.x >> 3;      // 0..95
    const int jh = blockIdx.x & 7;       // 0..7
    const int t  = threadIdx.x;          // 0..511

    f32x4 p[4];
    uint32_t qoff[4];
#pragma unroll
    for (int s = 0; s < 4; ++s) {
        uint32_t v  = (uint32_t)t + 512u * s;    // 0..2047
        uint32_t b  = v >> 7;
        uint32_t c4 = v & 127u;
        p[s]    = PQ4[((size_t)i * 16u + b) * 256u + c4];
        qoff[s] = b * 256u + 128u + c4;
    }

    const f32x4* qbase = PQ4 + (size_t)(jh * 12) * 16u * 256u;  // Q[j*16+b], j = jh*12
    f32x4* obase = out4 + ((size_t)(i * 96u + jh * 12u)) * 2048u + t;

#pragma unroll 4
    for (int j = 0; j < 12; ++j) {
        f32x4 q0 = qbase[qoff[0]];
        f32x4 q1 = qbase[qoff[1]];
        f32x4 q2 = qbase[qoff[2]];
        f32x4 q3 = qbase[qoff[3]];
        __builtin_nontemporal_store(p[0] + q0, obase);
        __builtin_nontemporal_store(p[1] + q1, obase + 512);
        __builtin_nontemporal_store(p[2] + q2, obase + 1024);
        __builtin_nontemporal_store(p[3] + q3, obase + 1536);
        qbase += 16u * 256u;   // next j
        obase += 2048u;
    }
}

extern "C" void kernel_launch(void* const* d_in, const int* in_sizes, int n_in,
                              void* d_out, int out_size, void* d_ws, size_t ws_size,
                              hipStream_t stream) {
    const float* x    = (const float*)d_in[0];
    const float* W    = (const float*)d_in[1];
    const float* bias = (const float*)d_in[2];
    float* out = (float*)d_out;

    float* PQ = (float*)d_ws;                      // 1536 x 1024 f32 = 6,291,456 B

    dim3 g(M_DIM / 128, N_DIM / 128);
    gemm_pq<<<g, 256, 0, stream>>>(x, W, bias, PQ);
    combine_k<<<768, 512, 0, stream>>>((const f32x4*)PQ, (f32x4*)out);
}

// Round 4
// 67.802 us; speedup vs baseline: 1.3101x; 1.3101x over previous
//
#include <hip/hip_runtime.h>
#include <hip/hip_bf16.h>
#include <stdint.h>

// CatLayer: out[i,j,b,c] = sum_k W[c,k] * leaky(concat(x_i, x_j))[k] + bias[c]
// Factorization: out[i,j,b,c] = P[i*16+b, c] + Q[j*16+b, c]  (bias folded into P)
//   [P|Q] = leaky(x).reshape(1536,512) @ [W[:, :512]^T | W[:, 512:]^T]
// K1: fused convert+GEMM, 96x64 tiles, 256 blocks (1/CU), K in 2 phases.
// K2: combine — q[12] hoisted to regs, then 12 dependency-free nt stores
//     (v2 store geometry, which benched best; v3's contiguous runs regressed).

typedef __attribute__((ext_vector_type(8))) short short8;
typedef __attribute__((ext_vector_type(4))) short short4v;
typedef __attribute__((ext_vector_type(4))) float f32x4;

#define L_DIM 96
#define B_DIM 16
#define C_DIM 512
#define M_DIM 1536   // L*B
#define K_DIM 512
#define N_DIM 1024   // 2*C

#define TM 96
#define TN 64
#define KPH 256      // K per LDS phase
#define ASTR 264     // LDS row stride in bf16 elems (256 + 8 pad, balanced banks)

__device__ inline unsigned short f32_to_bf16(float f) {
    union { float f; uint32_t u; } c; c.f = f;
    uint32_t u = c.u;
    uint32_t r = (u + 0x7FFFu + ((u >> 16) & 1u)) >> 16;  // RNE
    return (unsigned short)r;
}

// ---- fused GEMM: C[m][n] = sum_k leaky(x)[m][k]*Wt[n][k] (+bias for n<512) ----
__global__ __launch_bounds__(256) void gemm_pq(const float* __restrict__ x,
                                               const float* __restrict__ W,
                                               const float* __restrict__ bias,
                                               float* __restrict__ C) {
    __shared__ unsigned short As[TM * ASTR];   // 50688 B
    __shared__ unsigned short Bs[TN * ASTR];   // 33792 B  (84 KB total, 1 block/CU)
    const int bm = blockIdx.x;            // 0..15 (M tiles of 96)
    const int bn = blockIdx.y;            // 0..15 (N tiles of 64)
    const int tid = threadIdx.x;
    const int lane = tid & 63;
    const int w  = tid >> 6;
    const int wr = w >> 1, wc = w & 1;    // wave -> 48x32 quadrant
    const int l15 = lane & 15, l4 = lane >> 4;

    const float* xbase = x + (size_t)(bm * TM) * K_DIM;
    const float* wbase = (bn < 8) ? (W + (size_t)(bn * TN) * N_DIM)
                                  : (W + (size_t)(bn * TN - C_DIM) * N_DIM + C_DIM);

    f32x4 acc[3][2] = {};

    for (int ph = 0; ph < 2; ++ph) {
        __syncthreads();
        // stage A: 96 rows x 64 f32x4 chunks = 6144 chunks
#pragma unroll 4
        for (int r = 0; r < 24; ++r) {
            int q = tid + 256 * r;
            int row = q >> 6, kc4 = (q & 63) << 2;
            f32x4 v = *(const f32x4*)(xbase + (size_t)row * K_DIM + ph * KPH + kc4);
            short4v s;
#pragma unroll
            for (int e = 0; e < 4; ++e) {
                float f = v[e];
                f = f > 0.f ? f : 0.1f * f;
                s[e] = (short)f32_to_bf16(f);
            }
            *(short4v*)(&As[row * ASTR + kc4]) = s;
        }
        // stage B: 64 rows x 64 chunks = 4096 chunks
#pragma unroll 4
        for (int r = 0; r < 16; ++r) {
            int q = tid + 256 * r;
            int row = q >> 6, kc4 = (q & 63) << 2;
            f32x4 v = *(const f32x4*)(wbase + (size_t)row * N_DIM + ph * KPH + kc4);
            short4v s;
#pragma unroll
            for (int e = 0; e < 4; ++e) s[e] = (short)f32_to_bf16(v[e]);
            *(short4v*)(&Bs[row * ASTR + kc4]) = s;
        }
        __syncthreads();
        // compute: 8 kt steps, no barriers
#pragma unroll
        for (int kt = 0; kt < 8; ++kt) {
            short8 a[3], b[2];
#pragma unroll
            for (int m = 0; m < 3; ++m)
                a[m] = *(const short8*)(&As[(wr * 48 + m * 16 + l15) * ASTR + kt * 32 + l4 * 8]);
#pragma unroll
            for (int n = 0; n < 2; ++n)
                b[n] = *(const short8*)(&Bs[(wc * 32 + n * 16 + l15) * ASTR + kt * 32 + l4 * 8]);
#pragma unroll
            for (int m = 0; m < 3; ++m)
#pragma unroll
                for (int n = 0; n < 2; ++n)
                    acc[m][n] = __builtin_amdgcn_mfma_f32_16x16x32_bf16(a[m], b[n], acc[m][n], 0, 0, 0);
        }
    }

#pragma unroll
    for (int m = 0; m < 3; ++m) {
#pragma unroll
        for (int n = 0; n < 2; ++n) {
            int col = bn * TN + wc * 32 + n * 16 + l15;
            float bv = (bn < 8) ? bias[col] : 0.f;
#pragma unroll
            for (int e = 0; e < 4; ++e) {
                int row = bm * TM + wr * 48 + m * 16 + l4 * 4 + e;
                C[(size_t)row * N_DIM + col] = acc[m][n][e] + bv;
            }
        }
    }
}

// ---- combine v5: thread fixes (i,b,c4); q[12] hoisted; 12 nt stores ----
__global__ __launch_bounds__(256) void combine_k(const f32x4* __restrict__ PQ4,
                                                 f32x4* __restrict__ out4) {
    const int jh   = blockIdx.x & 7;              // j-octant
    const int rest = blockIdx.x >> 3;             // 0..767
    const int g    = rest * 256 + threadIdx.x;    // 0..196607
    const uint32_t c4 = (uint32_t)g & 127u;
    const uint32_t rg = (uint32_t)g >> 7;         // i*16+b, 0..1535
    const uint32_t b  = rg & 15u;
    const uint32_t i  = rg >> 4;

    const f32x4 p = PQ4[(size_t)rg * 256u + c4];          // P[i*16+b][c4]
    const int j0 = jh * 12;
    const f32x4* qb = PQ4 + ((size_t)(j0 * 16u + b)) * 256u + 128u + c4;

    f32x4 q[12];
#pragma unroll
    for (int j = 0; j < 12; ++j) q[j] = qb[(size_t)j * 4096u];   // +16 rows per j

    f32x4* ob = out4 + ((size_t)(i * 96u + (uint32_t)j0) * 16u + b) * 128u + c4;
#pragma unroll
    for (int j = 0; j < 12; ++j)
        __builtin_nontemporal_store(p + q[j], ob + (size_t)j * 2048u);  // +32KB per j
}

extern "C" void kernel_launch(void* const* d_in, const int* in_sizes, int n_in,
                              void* d_out, int out_size, void* d_ws, size_t ws_size,
                              hipStream_t stream) {
    const float* x    = (const float*)d_in[0];
    const float* W    = (const float*)d_in[1];
    const float* bias = (const float*)d_in[2];
    float* out = (float*)d_out;

    float* PQ = (float*)d_ws;                      // 1536 x 1024 f32 = 6,291,456 B

    dim3 g(M_DIM / TM, N_DIM / TN);                // 16 x 16 = 256 blocks
    gemm_pq<<<g, 256, 0, stream>>>(x, W, bias, PQ);
    combine_k<<<6144, 256, 0, stream>>>((const f32x4*)PQ, (f32x4*)out);
}